// Round 3
// baseline (474.729 us; speedup 1.0000x reference)
//
#include <hip/hip_runtime.h>
#include <math.h>

#define T_SEQ 1024
#define BATCH 4
#define NTOK  4096      // BATCH * T_SEQ
#define DM    512
#define NH    8
#define DH    64

#define PI_F  3.14159274101257324f   // float(math.pi)
#define TPI_F 6.28318548202514648f   // float(2*math.pi)

// ---------------------------------------------------------------------------
// Kernel 1: eta_range = max(max_b(max_t eta - min_t eta), 1e-6)
// ---------------------------------------------------------------------------
__global__ __launch_bounds__(256) void eta_range_kernel(
        const float* __restrict__ pcoords, float* __restrict__ er_out) {
    __shared__ float smin[256], smax[256];
    int t = threadIdx.x;
    float best = 0.0f;
    for (int b = 0; b < BATCH; ++b) {
        float mn = 3.0e38f, mx = -3.0e38f;
        for (int i = t; i < T_SEQ; i += 256) {
            float e = pcoords[(size_t)(b * T_SEQ + i) * 2 + 0];
            mn = fminf(mn, e);
            mx = fmaxf(mx, e);
        }
        smin[t] = mn; smax[t] = mx;
        __syncthreads();
        for (int s = 128; s > 0; s >>= 1) {
            if (t < s) {
                smin[t] = fminf(smin[t], smin[t + s]);
                smax[t] = fmaxf(smax[t], smax[t + s]);
            }
            __syncthreads();
        }
        if (t == 0) best = fmaxf(best, smax[0] - smin[0]);
        __syncthreads();
    }
    if (t == 0) er_out[0] = fmaxf(best, 1e-6f);
}

// ---------------------------------------------------------------------------
// Kernel 2: C[M=4096][512] = A[4096][512] @ W[512][512] + bias
// BM=128, BN=64, BK=16, 256 threads, 8x4 micro-tile per thread.
// ---------------------------------------------------------------------------
__global__ __launch_bounds__(256) void gemm512(
        const float* __restrict__ A, const float* __restrict__ W,
        const float* __restrict__ bias, float* __restrict__ C) {
    __shared__ float As[16][132];   // [k][m], stride 132*4=528B (16B mult)
    __shared__ float Bs[16][68];    // [k][n], stride 272B (16B mult)
    int t  = threadIdx.x;
    int m0 = blockIdx.y * 128;
    int n0 = blockIdx.x * 64;
    int tm = (t >> 4) * 8;          // broadcast within 16-lane groups
    int tn = (t & 15) * 4;
    float acc[8][4];
#pragma unroll
    for (int i = 0; i < 8; ++i)
#pragma unroll
        for (int j = 0; j < 4; ++j) acc[i][j] = 0.0f;

    for (int kb = 0; kb < DM; kb += 16) {
#pragma unroll
        for (int i = 0; i < 2; ++i) {               // A tile: 128x16
            int idx = t * 2 + i;                    // 0..511 float4s
            int row = idx >> 2;                     // m-local 0..127
            int c4  = (idx & 3) * 4;                // k-local 0,4,8,12
            float4 v = *(const float4*)(A + (size_t)(m0 + row) * DM + kb + c4);
            As[c4 + 0][row] = v.x; As[c4 + 1][row] = v.y;
            As[c4 + 2][row] = v.z; As[c4 + 3][row] = v.w;
        }
        {                                           // B tile: 16x64
            int row = t >> 4;                       // k-local 0..15
            int c4  = (t & 15) * 4;                 // n-local
            *(float4*)&Bs[row][c4] =
                *(const float4*)(W + (size_t)(kb + row) * DM + n0 + c4);
        }
        __syncthreads();
#pragma unroll
        for (int k = 0; k < 16; ++k) {
            float4 a0 = *(const float4*)&As[k][tm];
            float4 a1 = *(const float4*)&As[k][tm + 4];
            float4 bv = *(const float4*)&Bs[k][tn];
            float a[8] = {a0.x, a0.y, a0.z, a0.w, a1.x, a1.y, a1.z, a1.w};
            float bb[4] = {bv.x, bv.y, bv.z, bv.w};
#pragma unroll
            for (int i = 0; i < 8; ++i)
#pragma unroll
                for (int j = 0; j < 4; ++j)
                    acc[i][j] = fmaf(a[i], bb[j], acc[i][j]);
        }
        __syncthreads();
    }
    float4 bv = *(const float4*)(bias + n0 + tn);
#pragma unroll
    for (int i = 0; i < 8; ++i) {
        float4 o;
        o.x = acc[i][0] + bv.x; o.y = acc[i][1] + bv.y;
        o.z = acc[i][2] + bv.z; o.w = acc[i][3] + bv.w;
        *(float4*)(C + (size_t)(m0 + tm + i) * DM + n0 + tn) = o;
    }
}

// ---------------------------------------------------------------------------
// Kernel 3: fused attention with on-the-fly RPE bias, flash-style.
// One block per (query-tile of 64, head, batch). 256 threads.
// ---------------------------------------------------------------------------
__device__ __forceinline__ float wrap_phi(float x) {
    // match jnp.mod(x + pi, 2pi) - pi  (divisor-sign semantics)
    float m = fmodf(x + PI_F, TPI_F);
    if (m < 0.0f) m += TPI_F;
    return m - PI_F;
}

__global__ __launch_bounds__(256) void attn_kernel(
        const float* __restrict__ q, const float* __restrict__ k,
        const float* __restrict__ v, const float* __restrict__ pcoords,
        const float* __restrict__ rpe, const float* __restrict__ er_ptr,
        float* __restrict__ out) {
    __shared__ float Qs[64][68];    // [d][r]
    __shared__ float Ks[64][68];    // [d][c]
    __shared__ float Vs[64][68];    // [c][d]
    __shared__ float Ps[64][68];    // [c][r]  (scores -> probs)
    __shared__ float etaq[64], phiq[64], etak[64], phik[64];
    __shared__ float tbl[64];
    __shared__ float smax[4][64], ssum[4][64];
    __shared__ float mrow[64], lrow[64], arow[64];

    int t  = threadIdx.x;
    int qt = blockIdx.x;            // 0..15 query tile
    int h  = blockIdx.y;            // 0..7
    int b  = blockIdx.z;            // 0..3
    int q0 = qt * 64;
    const float er = er_ptr[0];

    // load Q tile (transposed into [d][r]), coords, table column h
#pragma unroll
    for (int i = 0; i < 4; ++i) {
        int idx = t + 256 * i;
        int row = idx >> 4;
        int c4  = (idx & 15) * 4;
        float4 vv = *(const float4*)(q + (size_t)(b * T_SEQ + q0 + row) * DM + h * DH + c4);
        Qs[c4 + 0][row] = vv.x; Qs[c4 + 1][row] = vv.y;
        Qs[c4 + 2][row] = vv.z; Qs[c4 + 3][row] = vv.w;
    }
    if (t < 64) {
        int row = b * T_SEQ + q0 + t;
        etaq[t] = pcoords[(size_t)row * 2 + 0];
        phiq[t] = pcoords[(size_t)row * 2 + 1];
        tbl[t]  = rpe[(size_t)t * NH + h];
        mrow[t] = -3.0e38f;
        lrow[t] = 0.0f;
    }
    int sr = (t >> 4) * 4;   // rows (queries) this thread owns
    int sc = (t & 15) * 4;   // cols (keys) in S phase == dims in O phase
    float oacc[4][4];
#pragma unroll
    for (int i = 0; i < 4; ++i)
#pragma unroll
        for (int j = 0; j < 4; ++j) oacc[i][j] = 0.0f;
    __syncthreads();

    for (int kb = 0; kb < 16; ++kb) {
        // ---- phase 1: load K (transposed), V (natural), key coords ----
#pragma unroll
        for (int i = 0; i < 4; ++i) {
            int idx = t + 256 * i;
            int row = idx >> 4;
            int c4  = (idx & 15) * 4;
            size_t gro = (size_t)(b * T_SEQ + kb * 64 + row) * DM + h * DH + c4;
            float4 kv = *(const float4*)(k + gro);
            Ks[c4 + 0][row] = kv.x; Ks[c4 + 1][row] = kv.y;
            Ks[c4 + 2][row] = kv.z; Ks[c4 + 3][row] = kv.w;
            *(float4*)&Vs[row][c4] = *(const float4*)(v + gro);
        }
        if (t < 64) {
            int row = b * T_SEQ + kb * 64 + t;
            etak[t] = pcoords[(size_t)row * 2 + 0];
            phik[t] = pcoords[(size_t)row * 2 + 1];
        }
        __syncthreads();

        // ---- phase 2: S = (Q K^T) * scale + rpe_bias  -> Ps[c][r] ----
        float s_acc[4][4];
#pragma unroll
        for (int i = 0; i < 4; ++i)
#pragma unroll
            for (int j = 0; j < 4; ++j) s_acc[i][j] = 0.0f;
#pragma unroll 16
        for (int kk = 0; kk < 64; ++kk) {
            float4 qv = *(const float4*)&Qs[kk][sr];
            float4 kv = *(const float4*)&Ks[kk][sc];
            float qa[4] = {qv.x, qv.y, qv.z, qv.w};
            float ka[4] = {kv.x, kv.y, kv.z, kv.w};
#pragma unroll
            for (int i = 0; i < 4; ++i)
#pragma unroll
                for (int j = 0; j < 4; ++j)
                    s_acc[i][j] = fmaf(qa[i], ka[j], s_acc[i][j]);
        }
#pragma unroll
        for (int i = 0; i < 4; ++i) {
            float ei = etaq[sr + i];
            float pq = phiq[sr + i];
#pragma unroll
            for (int j = 0; j < 4; ++j) {
                float re = ei - etak[sc + j];
                float rp = wrap_phi(pq - phik[sc + j]);
                int eb = (int)(re / er * 16.0f);      // IEEE div; trunc toward 0
                int pb = (int)(rp / PI_F * 16.0f);
                eb = eb < -16 ? -16 : (eb > 15 ? 15 : eb);
                pb = pb < -16 ? -16 : (pb > 15 ? 15 : pb);
                float bias = tbl[eb + 16] + tbl[pb + 48];
                Ps[sc + j][sr + i] = s_acc[i][j] * 0.125f + bias;
            }
        }
        __syncthreads();

        // ---- phase 3: online softmax row stats + exponentiate ----
        {
            int r  = t & 63;
            int qd = t >> 6;
            float pm = -3.0e38f;
#pragma unroll
            for (int i = 0; i < 16; ++i) pm = fmaxf(pm, Ps[qd * 16 + i][r]);
            smax[qd][r] = pm;
            __syncthreads();
            float mold = mrow[r];
            float mnew = fmaxf(fmaxf(fmaxf(smax[0][r], smax[1][r]),
                                     fmaxf(smax[2][r], smax[3][r])), mold);
            float psum = 0.0f;
#pragma unroll
            for (int i = 0; i < 16; ++i) {
                int c = qd * 16 + i;
                float p = __expf(Ps[c][r] - mnew);
                Ps[c][r] = p;
                psum += p;
            }
            ssum[qd][r] = psum;
            __syncthreads();
            if (qd == 0) {
                float alpha = __expf(mold - mnew);
                arow[r] = alpha;
                lrow[r] = lrow[r] * alpha +
                          ssum[0][r] + ssum[1][r] + ssum[2][r] + ssum[3][r];
                mrow[r] = mnew;
            }
            __syncthreads();
        }

        // ---- phase 4: O = O*alpha + P @ V ----
        {
            float al[4];
#pragma unroll
            for (int i = 0; i < 4; ++i) al[i] = arow[sr + i];
#pragma unroll
            for (int i = 0; i < 4; ++i)
#pragma unroll
                for (int j = 0; j < 4; ++j) oacc[i][j] *= al[i];
#pragma unroll 16
            for (int c = 0; c < 64; ++c) {
                float4 pv = *(const float4*)&Ps[c][sr];
                float4 vv = *(const float4*)&Vs[c][sc];
                float pa[4] = {pv.x, pv.y, pv.z, pv.w};
                float va[4] = {vv.x, vv.y, vv.z, vv.w};
#pragma unroll
                for (int i = 0; i < 4; ++i)
#pragma unroll
                    for (int j = 0; j < 4; ++j)
                        oacc[i][j] = fmaf(pa[i], va[j], oacc[i][j]);
            }
            __syncthreads();
        }
    }

    // epilogue: divide by l, write [B,T,H*DH]
#pragma unroll
    for (int i = 0; i < 4; ++i) {
        float inv = 1.0f / lrow[sr + i];
        float4 o;
        o.x = oacc[i][0] * inv; o.y = oacc[i][1] * inv;
        o.z = oacc[i][2] * inv; o.w = oacc[i][3] * inv;
        *(float4*)(out + (size_t)(b * T_SEQ + q0 + sr + i) * DM + h * DH + sc) = o;
    }
}

// ---------------------------------------------------------------------------
extern "C" void kernel_launch(void* const* d_in, const int* in_sizes, int n_in,
                              void* d_out, int out_size, void* d_ws, size_t ws_size,
                              hipStream_t stream) {
    const float* p       = (const float*)d_in[0];
    const float* pcoords = (const float*)d_in[1];
    const float* rpe     = (const float*)d_in[2];
    const float* wq_w    = (const float*)d_in[3];
    const float* wq_b    = (const float*)d_in[4];
    const float* wk_w    = (const float*)d_in[5];
    const float* wk_b    = (const float*)d_in[6];
    const float* wv_w    = (const float*)d_in[7];
    const float* wv_b    = (const float*)d_in[8];
    const float* wo_w    = (const float*)d_in[9];
    const float* wo_b    = (const float*)d_in[10];
    float* out = (float*)d_out;

    float* qb   = (float*)d_ws;
    float* kb   = qb + (size_t)NTOK * DM;
    float* vb   = kb + (size_t)NTOK * DM;
    float* attn = vb + (size_t)NTOK * DM;
    float* er   = attn + (size_t)NTOK * DM;

    eta_range_kernel<<<1, 256, 0, stream>>>(pcoords, er);

    dim3 gg(DM / 64, NTOK / 128);
    gemm512<<<gg, 256, 0, stream>>>(p, wq_w, wq_b, qb);
    gemm512<<<gg, 256, 0, stream>>>(p, wk_w, wk_b, kb);
    gemm512<<<gg, 256, 0, stream>>>(p, wv_w, wv_b, vb);

    attn_kernel<<<dim3(16, NH, BATCH), 256, 0, stream>>>(
        qb, kb, vb, pcoords, rpe, er, attn);

    gemm512<<<gg, 256, 0, stream>>>(attn, wo_w, wo_b, out);
}

// Round 4
// 321.248 us; speedup vs baseline: 1.4778x; 1.4778x over previous
//
#include <hip/hip_runtime.h>
#include <math.h>

#define T_SEQ 1024
#define BATCH 4
#define NTOK  4096      // BATCH * T_SEQ
#define DM    512
#define NH    8
#define DH    64

#define PI_F  3.14159274101257324f   // float(math.pi)
#define TPI_F 6.28318548202514648f   // float(2*math.pi)

typedef __attribute__((ext_vector_type(8))) short bf16x8;
typedef __attribute__((ext_vector_type(4))) float f32x4;

__device__ __forceinline__ ushort f2bf(float x) {   // RNE fp32 -> bf16
    uint u = __float_as_uint(x);
    return (ushort)((u + 0x7fffu + ((u >> 16) & 1u)) >> 16);
}

// ---------------------------------------------------------------------------
// Kernel 1: eta_range = max(max_b(max_t eta - min_t eta), 1e-6)
// ---------------------------------------------------------------------------
__global__ __launch_bounds__(256) void eta_range_kernel(
        const float* __restrict__ pcoords, float* __restrict__ er_out) {
    __shared__ float smin[256], smax[256];
    int t = threadIdx.x;
    float best = 0.0f;
    for (int b = 0; b < BATCH; ++b) {
        float mn = 3.0e38f, mx = -3.0e38f;
        for (int i = t; i < T_SEQ; i += 256) {
            float e = pcoords[(size_t)(b * T_SEQ + i) * 2 + 0];
            mn = fminf(mn, e);
            mx = fmaxf(mx, e);
        }
        smin[t] = mn; smax[t] = mx;
        __syncthreads();
        for (int s = 128; s > 0; s >>= 1) {
            if (t < s) {
                smin[t] = fminf(smin[t], smin[t + s]);
                smax[t] = fmaxf(smax[t], smax[t + s]);
            }
            __syncthreads();
        }
        if (t == 0) best = fmaxf(best, smax[0] - smin[0]);
        __syncthreads();
    }
    if (t == 0) er_out[0] = fmaxf(best, 1e-6f);
}

// ---------------------------------------------------------------------------
// Kernel 2a: fp32 -> bf16 cast, 4 elems/thread, exact-size grid.
// ---------------------------------------------------------------------------
__global__ __launch_bounds__(256) void cvt_bf16(
        const float* __restrict__ in, ushort* __restrict__ out) {
    int i = blockIdx.x * 256 + threadIdx.x;
    float4 v = ((const float4*)in)[i];
    ushort4 o;
    o.x = f2bf(v.x); o.y = f2bf(v.y); o.z = f2bf(v.z); o.w = f2bf(v.w);
    ((ushort4*)out)[i] = o;
}

// ---------------------------------------------------------------------------
// Kernel 2b: W[k][n] fp32 -> Wt[n][k] bf16 (transpose), 4 weights in one
// launch via blockIdx.z. 64x64 tiles through LDS.
// ---------------------------------------------------------------------------
__global__ __launch_bounds__(256) void cvtT_bf16(
        const float* __restrict__ w0, const float* __restrict__ w1,
        const float* __restrict__ w2, const float* __restrict__ w3,
        ushort* __restrict__ o0, ushort* __restrict__ o1,
        ushort* __restrict__ o2, ushort* __restrict__ o3) {
    const float* W; ushort* O;
    switch (blockIdx.z) {
        case 0:  W = w0; O = o0; break;
        case 1:  W = w1; O = o1; break;
        case 2:  W = w2; O = o2; break;
        default: W = w3; O = o3; break;
    }
    __shared__ ushort Ls[64][72];
    int t  = threadIdx.x;
    int n0 = blockIdx.x * 64;
    int k0 = blockIdx.y * 64;
#pragma unroll
    for (int i = 0; i < 4; ++i) {
        int kr = (t >> 4) + i * 16;
        float4 v = *(const float4*)(W + (size_t)(k0 + kr) * DM + n0 + (t & 15) * 4);
        Ls[(t & 15) * 4 + 0][kr] = f2bf(v.x);
        Ls[(t & 15) * 4 + 1][kr] = f2bf(v.y);
        Ls[(t & 15) * 4 + 2][kr] = f2bf(v.z);
        Ls[(t & 15) * 4 + 3][kr] = f2bf(v.w);
    }
    __syncthreads();
#pragma unroll
    for (int i = 0; i < 4; ++i) {
        int nl = (t >> 4) + i * 16;
        int k4 = (t & 15) * 4;
        ushort4 u;
        u.x = Ls[nl][k4 + 0]; u.y = Ls[nl][k4 + 1];
        u.z = Ls[nl][k4 + 2]; u.w = Ls[nl][k4 + 3];
        *(ushort4*)(O + (size_t)(n0 + nl) * DM + k0 + k4) = u;
    }
}

// ---------------------------------------------------------------------------
// Kernel 3: bf16-MFMA GEMM  C[4096][512] = A[4096][512] @ Wt^T + bias
//   A: bf16 [m][k] row-major; Bt: bf16 [n][k] (pre-transposed weight).
//   BM=BN=BK=64, 256 threads (4 waves, 2x2), wave tile 32x32,
//   16x16x32 bf16 MFMA, fp32 accumulate, fp32 output.
//   Staging via global_load_lds(16B) with XOR slot-swizzle applied on the
//   global source (linear LDS dest), same XOR on ds_read (rule #21).
// ---------------------------------------------------------------------------
__global__ __launch_bounds__(256) void gemm_mfma(
        const ushort* __restrict__ A, const ushort* __restrict__ Bt,
        const float* __restrict__ bias, float* __restrict__ C) {
    __shared__ ushort As[64 * 64];
    __shared__ ushort Bs[64 * 64];
    int t  = threadIdx.x;
    int w  = t >> 6;            // wave 0..3
    int ln = t & 63;
    int wr = w >> 1, wc = w & 1;
    int n0 = blockIdx.x * 64;
    int m0 = blockIdx.y * 64;

    f32x4 acc[2][2];
#pragma unroll
    for (int i = 0; i < 2; ++i)
#pragma unroll
        for (int j = 0; j < 2; ++j) acc[i][j] = (f32x4)0.0f;

    int row16 = ln & 15, kg = ln >> 4;

    for (int kb = 0; kb < DM; kb += 64) {
#pragma unroll
        for (int issue = 0; issue < 2; ++issue) {
            int chunk = issue * 256 + w * 64 + ln;      // 0..511 16B chunks
            int r = chunk >> 3, s = chunk & 7;
            int gcol = kb + ((s ^ (r & 7)) * 8);        // pre-swizzled source
            const ushort* ga = A  + (size_t)(m0 + r) * DM + gcol;
            const ushort* gb = Bt + (size_t)(n0 + r) * DM + gcol;
            __builtin_amdgcn_global_load_lds((const void*)ga,
                (void*)(As + (issue * 256 + w * 64) * 8), 16, 0, 0);
            __builtin_amdgcn_global_load_lds((const void*)gb,
                (void*)(Bs + (issue * 256 + w * 64) * 8), 16, 0, 0);
        }
        __syncthreads();
#pragma unroll
        for (int kk = 0; kk < 2; ++kk) {
            int swz = (kk * 32 + kg * 8) ^ ((row16 & 7) << 3);  // ushort idx in row
            bf16x8 af[2], bfr[2];
#pragma unroll
            for (int f = 0; f < 2; ++f) {
                int arow = 32 * wr + f * 16 + row16;
                af[f]  = *(const bf16x8*)&As[arow * 64 + swz];
                int brow = 32 * wc + f * 16 + row16;
                bfr[f] = *(const bf16x8*)&Bs[brow * 64 + swz];
            }
#pragma unroll
            for (int fr = 0; fr < 2; ++fr)
#pragma unroll
                for (int fc = 0; fc < 2; ++fc)
                    acc[fr][fc] = __builtin_amdgcn_mfma_f32_16x16x32_bf16(
                        af[fr], bfr[fc], acc[fr][fc], 0, 0, 0);
        }
        __syncthreads();
    }

    // epilogue: C/D layout col=lane&15, row=(lane>>4)*4+reg
    int col = ln & 15, rbase = (ln >> 4) * 4;
#pragma unroll
    for (int fc = 0; fc < 2; ++fc) {
        float bv = bias[n0 + 32 * wc + fc * 16 + col];
#pragma unroll
        for (int fr = 0; fr < 2; ++fr) {
#pragma unroll
            for (int reg = 0; reg < 4; ++reg) {
                int m = m0 + 32 * wr + fr * 16 + rbase + reg;
                int n = n0 + 32 * wc + fc * 16 + col;
                C[(size_t)m * DM + n] = acc[fr][fc][reg] + bv;
            }
        }
    }
}

// ---------------------------------------------------------------------------
// Kernel 4: fused attention with on-the-fly RPE bias, flash-style. fp32.
// One block per (query-tile of 64, head, batch). 256 threads.
// ---------------------------------------------------------------------------
__device__ __forceinline__ float wrap_phi(float x) {
    // match jnp.mod(x + pi, 2pi) - pi  (divisor-sign semantics)
    float m = fmodf(x + PI_F, TPI_F);
    if (m < 0.0f) m += TPI_F;
    return m - PI_F;
}

__global__ __launch_bounds__(256) void attn_kernel(
        const float* __restrict__ q, const float* __restrict__ k,
        const float* __restrict__ v, const float* __restrict__ pcoords,
        const float* __restrict__ rpe, const float* __restrict__ er_ptr,
        float* __restrict__ out) {
    __shared__ float Qs[64][68];    // [d][r]
    __shared__ float Ks[64][68];    // [d][c]
    __shared__ float Vs[64][68];    // [c][d]
    __shared__ float Ps[64][68];    // [c][r]  (scores -> probs)
    __shared__ float etaq[64], phiq[64], etak[64], phik[64];
    __shared__ float tbl[64];
    __shared__ float smax[4][64], ssum[4][64];
    __shared__ float mrow[64], lrow[64], arow[64];

    int t  = threadIdx.x;
    int qt = blockIdx.x;            // 0..15 query tile
    int h  = blockIdx.y;            // 0..7
    int b  = blockIdx.z;            // 0..3
    int q0 = qt * 64;
    const float er = er_ptr[0];

#pragma unroll
    for (int i = 0; i < 4; ++i) {
        int idx = t + 256 * i;
        int row = idx >> 4;
        int c4  = (idx & 15) * 4;
        float4 vv = *(const float4*)(q + (size_t)(b * T_SEQ + q0 + row) * DM + h * DH + c4);
        Qs[c4 + 0][row] = vv.x; Qs[c4 + 1][row] = vv.y;
        Qs[c4 + 2][row] = vv.z; Qs[c4 + 3][row] = vv.w;
    }
    if (t < 64) {
        int row = b * T_SEQ + q0 + t;
        etaq[t] = pcoords[(size_t)row * 2 + 0];
        phiq[t] = pcoords[(size_t)row * 2 + 1];
        tbl[t]  = rpe[(size_t)t * NH + h];
        mrow[t] = -3.0e38f;
        lrow[t] = 0.0f;
    }
    int sr = (t >> 4) * 4;   // rows (queries) this thread owns
    int sc = (t & 15) * 4;   // cols (keys) in S phase == dims in O phase
    float oacc[4][4];
#pragma unroll
    for (int i = 0; i < 4; ++i)
#pragma unroll
        for (int j = 0; j < 4; ++j) oacc[i][j] = 0.0f;
    __syncthreads();

    for (int kb = 0; kb < 16; ++kb) {
        // ---- phase 1: load K (transposed), V (natural), key coords ----
#pragma unroll
        for (int i = 0; i < 4; ++i) {
            int idx = t + 256 * i;
            int row = idx >> 4;
            int c4  = (idx & 15) * 4;
            size_t gro = (size_t)(b * T_SEQ + kb * 64 + row) * DM + h * DH + c4;
            float4 kv = *(const float4*)(k + gro);
            Ks[c4 + 0][row] = kv.x; Ks[c4 + 1][row] = kv.y;
            Ks[c4 + 2][row] = kv.z; Ks[c4 + 3][row] = kv.w;
            *(float4*)&Vs[row][c4] = *(const float4*)(v + gro);
        }
        if (t < 64) {
            int row = b * T_SEQ + kb * 64 + t;
            etak[t] = pcoords[(size_t)row * 2 + 0];
            phik[t] = pcoords[(size_t)row * 2 + 1];
        }
        __syncthreads();

        // ---- phase 2: S = (Q K^T) * scale + rpe_bias  -> Ps[c][r] ----
        float s_acc[4][4];
#pragma unroll
        for (int i = 0; i < 4; ++i)
#pragma unroll
            for (int j = 0; j < 4; ++j) s_acc[i][j] = 0.0f;
#pragma unroll 16
        for (int kk = 0; kk < 64; ++kk) {
            float4 qv = *(const float4*)&Qs[kk][sr];
            float4 kv = *(const float4*)&Ks[kk][sc];
            float qa[4] = {qv.x, qv.y, qv.z, qv.w};
            float ka[4] = {kv.x, kv.y, kv.z, kv.w};
#pragma unroll
            for (int i = 0; i < 4; ++i)
#pragma unroll
                for (int j = 0; j < 4; ++j)
                    s_acc[i][j] = fmaf(qa[i], ka[j], s_acc[i][j]);
        }
        // bias + vectorized transposed store (4x b128, bank-balanced)
        {
            float ei[4], pqv[4];
#pragma unroll
            for (int i = 0; i < 4; ++i) { ei[i] = etaq[sr + i]; pqv[i] = phiq[sr + i]; }
#pragma unroll
            for (int j = 0; j < 4; ++j) {
                float ek = etak[sc + j], pk = phik[sc + j];
                float tmp[4];
#pragma unroll
                for (int i = 0; i < 4; ++i) {
                    float re = ei[i] - ek;
                    float rp = wrap_phi(pqv[i] - pk);
                    int eb  = (int)(re / er * 16.0f);   // IEEE div; trunc toward 0
                    int pbn = (int)(rp / PI_F * 16.0f);
                    eb  = eb  < -16 ? -16 : (eb  > 15 ? 15 : eb);
                    pbn = pbn < -16 ? -16 : (pbn > 15 ? 15 : pbn);
                    tmp[i] = s_acc[i][j] * 0.125f + tbl[eb + 16] + tbl[pbn + 48];
                }
                float4 o;
                o.x = tmp[0]; o.y = tmp[1]; o.z = tmp[2]; o.w = tmp[3];
                *(float4*)&Ps[sc + j][sr] = o;
            }
        }
        __syncthreads();

        // ---- phase 3: online softmax row stats + exponentiate ----
        {
            int r  = t & 63;
            int qd = t >> 6;
            float pm = -3.0e38f;
#pragma unroll
            for (int i = 0; i < 16; ++i) pm = fmaxf(pm, Ps[qd * 16 + i][r]);
            smax[qd][r] = pm;
            __syncthreads();
            float mold = mrow[r];
            float mnew = fmaxf(fmaxf(fmaxf(smax[0][r], smax[1][r]),
                                     fmaxf(smax[2][r], smax[3][r])), mold);
            float psum = 0.0f;
#pragma unroll
            for (int i = 0; i < 16; ++i) {
                int c = qd * 16 + i;
                float p = __expf(Ps[c][r] - mnew);
                Ps[c][r] = p;
                psum += p;
            }
            ssum[qd][r] = psum;
            __syncthreads();
            if (qd == 0) {
                float alpha = __expf(mold - mnew);
                arow[r] = alpha;
                lrow[r] = lrow[r] * alpha +
                          ssum[0][r] + ssum[1][r] + ssum[2][r] + ssum[3][r];
                mrow[r] = mnew;
            }
            __syncthreads();
        }

        // ---- phase 4: O = O*alpha + P @ V ----
        {
            float al[4];
#pragma unroll
            for (int i = 0; i < 4; ++i) al[i] = arow[sr + i];
#pragma unroll
            for (int i = 0; i < 4; ++i)
#pragma unroll
                for (int j = 0; j < 4; ++j) oacc[i][j] *= al[i];
#pragma unroll 16
            for (int c = 0; c < 64; ++c) {
                float4 pv = *(const float4*)&Ps[c][sr];
                float4 vv = *(const float4*)&Vs[c][sc];
                float pa[4] = {pv.x, pv.y, pv.z, pv.w};
                float va[4] = {vv.x, vv.y, vv.z, vv.w};
#pragma unroll
                for (int i = 0; i < 4; ++i)
#pragma unroll
                    for (int j = 0; j < 4; ++j)
                        oacc[i][j] = fmaf(pa[i], va[j], oacc[i][j]);
            }
            __syncthreads();
        }
    }

    // epilogue: divide by l, write [B,T,H*DH]
#pragma unroll
    for (int i = 0; i < 4; ++i) {
        float inv = 1.0f / lrow[sr + i];
        float4 o;
        o.x = oacc[i][0] * inv; o.y = oacc[i][1] * inv;
        o.z = oacc[i][2] * inv; o.w = oacc[i][3] * inv;
        *(float4*)(out + (size_t)(b * T_SEQ + q0 + sr + i) * DM + h * DH + sc) = o;
    }
}

// ---------------------------------------------------------------------------
extern "C" void kernel_launch(void* const* d_in, const int* in_sizes, int n_in,
                              void* d_out, int out_size, void* d_ws, size_t ws_size,
                              hipStream_t stream) {
    const float* p       = (const float*)d_in[0];
    const float* pcoords = (const float*)d_in[1];
    const float* rpe     = (const float*)d_in[2];
    const float* wq_w    = (const float*)d_in[3];
    const float* wq_b    = (const float*)d_in[4];
    const float* wk_w    = (const float*)d_in[5];
    const float* wk_b    = (const float*)d_in[6];
    const float* wv_w    = (const float*)d_in[7];
    const float* wv_b    = (const float*)d_in[8];
    const float* wo_w    = (const float*)d_in[9];
    const float* wo_b    = (const float*)d_in[10];
    float* out = (float*)d_out;

    const size_t NE = (size_t)NTOK * DM;     // 2M elems
    float*  qb    = (float*)d_ws;
    float*  kbuf  = qb + NE;
    float*  vbuf  = kbuf + NE;
    float*  attnf = vbuf + NE;
    ushort* pb    = (ushort*)(attnf + NE);   // bf16 p
    ushort* ab    = pb + NE;                 // bf16 attn out
    ushort* wt0   = ab + NE;                 // bf16 transposed weights
    ushort* wt1   = wt0 + (size_t)DM * DM;
    ushort* wt2   = wt1 + (size_t)DM * DM;
    ushort* wt3   = wt2 + (size_t)DM * DM;
    float*  er    = (float*)(wt3 + (size_t)DM * DM);

    eta_range_kernel<<<1, 256, 0, stream>>>(pcoords, er);
    cvt_bf16<<<NE / 1024, 256, 0, stream>>>(p, pb);
    cvtT_bf16<<<dim3(8, 8, 4), 256, 0, stream>>>(
        wq_w, wk_w, wv_w, wo_w, wt0, wt1, wt2, wt3);

    dim3 gg(DM / 64, NTOK / 64);
    gemm_mfma<<<gg, 256, 0, stream>>>(pb, wt0, wq_b, qb);
    gemm_mfma<<<gg, 256, 0, stream>>>(pb, wt1, wk_b, kbuf);
    gemm_mfma<<<gg, 256, 0, stream>>>(pb, wt2, wv_b, vbuf);

    attn_kernel<<<dim3(16, NH, BATCH), 256, 0, stream>>>(
        qb, kbuf, vbuf, pcoords, rpe, er, attnf);

    cvt_bf16<<<NE / 1024, 256, 0, stream>>>(attnf, ab);
    gemm_mfma<<<gg, 256, 0, stream>>>(ab, wt3, wo_b, out);
}

// Round 5
// 177.109 us; speedup vs baseline: 2.6804x; 1.8138x over previous
//
#include <hip/hip_runtime.h>
#include <math.h>

#define T_SEQ 1024
#define BATCH 4
#define NTOK  4096      // BATCH * T_SEQ
#define DM    512
#define NH    8
#define DH    64

#define PI_F  3.14159274101257324f   // float(math.pi)
#define TPI_F 6.28318548202514648f   // float(2*math.pi)

typedef __attribute__((ext_vector_type(8))) short bf16x8;
typedef __attribute__((ext_vector_type(4))) float f32x4;

__device__ __forceinline__ ushort f2bf(float x) {   // RNE fp32 -> bf16
    uint u = __float_as_uint(x);
    return (ushort)((u + 0x7fffu + ((u >> 16) & 1u)) >> 16);
}

__device__ __forceinline__ float wrap_phi(float x) {
    // match jnp.mod(x + pi, 2pi) - pi  (divisor-sign semantics)
    float m = fmodf(x + PI_F, TPI_F);
    if (m < 0.0f) m += TPI_F;
    return m - PI_F;
}

// ---------------------------------------------------------------------------
// Kernel 1: eta_range = max(max_b(max_t eta - min_t eta), 1e-6)
// ---------------------------------------------------------------------------
__global__ __launch_bounds__(256) void eta_range_kernel(
        const float* __restrict__ pcoords, float* __restrict__ er_out) {
    __shared__ float smin[256], smax[256];
    int t = threadIdx.x;
    float best = 0.0f;
    for (int b = 0; b < BATCH; ++b) {
        float mn = 3.0e38f, mx = -3.0e38f;
        for (int i = t; i < T_SEQ; i += 256) {
            float e = pcoords[(size_t)(b * T_SEQ + i) * 2 + 0];
            mn = fminf(mn, e);
            mx = fmaxf(mx, e);
        }
        smin[t] = mn; smax[t] = mx;
        __syncthreads();
        for (int s = 128; s > 0; s >>= 1) {
            if (t < s) {
                smin[t] = fminf(smin[t], smin[t + s]);
                smax[t] = fmaxf(smax[t], smax[t + s]);
            }
            __syncthreads();
        }
        if (t == 0) best = fmaxf(best, smax[0] - smin[0]);
        __syncthreads();
    }
    if (t == 0) er_out[0] = fmaxf(best, 1e-6f);
}

// ---------------------------------------------------------------------------
// Kernel 2: packed RPE bins [B,T,T] u16 = eta_idx | (phi_idx<<8).
// Head-independent — computed ONCE (the old kernel recomputed it 8x).
// ---------------------------------------------------------------------------
__global__ __launch_bounds__(256) void bins_kernel(
        const float* __restrict__ pcoords, const float* __restrict__ er_ptr,
        ushort* __restrict__ bins) {
    int t  = threadIdx.x;
    int b  = blockIdx.y;
    int q  = blockIdx.x * 16 + (t >> 4);
    int k0 = (t & 15) * 64;
    float er = er_ptr[0];
    float2 qc = *(const float2*)(pcoords + (size_t)(b * T_SEQ + q) * 2);
    ushort* orow = bins + ((size_t)(b * T_SEQ + q)) * T_SEQ + k0;
    for (int j = 0; j < 64; j += 4) {
        ushort tmp[4];
#pragma unroll
        for (int jj = 0; jj < 4; ++jj) {
            float2 kc = *(const float2*)(pcoords + (size_t)(b * T_SEQ + k0 + j + jj) * 2);
            float re = qc.x - kc.x;
            float rp = wrap_phi(qc.y - kc.y);
            int eb = (int)(re / er * 16.0f);    // IEEE div; trunc toward 0
            int pb = (int)(rp / PI_F * 16.0f);
            eb = eb < -16 ? -16 : (eb > 15 ? 15 : eb);
            pb = pb < -16 ? -16 : (pb > 15 ? 15 : pb);
            tmp[jj] = (ushort)((eb + 16) | ((pb + 48) << 8));
        }
        ushort4 u; u.x = tmp[0]; u.y = tmp[1]; u.z = tmp[2]; u.w = tmp[3];
        *(ushort4*)&orow[j] = u;
    }
}

// ---------------------------------------------------------------------------
// Kernel 3a: fp32 -> bf16 cast (p only)
// ---------------------------------------------------------------------------
__global__ __launch_bounds__(256) void cvt_bf16(
        const float* __restrict__ in, ushort* __restrict__ out) {
    int i = blockIdx.x * 256 + threadIdx.x;
    float4 v = ((const float4*)in)[i];
    ushort4 o;
    o.x = f2bf(v.x); o.y = f2bf(v.y); o.z = f2bf(v.z); o.w = f2bf(v.w);
    ((ushort4*)out)[i] = o;
}

// ---------------------------------------------------------------------------
// Kernel 3b: W[k][n] fp32 -> Wt[n][k] bf16 (transpose), 4 weights per launch.
// ---------------------------------------------------------------------------
__global__ __launch_bounds__(256) void cvtT_bf16(
        const float* __restrict__ w0, const float* __restrict__ w1,
        const float* __restrict__ w2, const float* __restrict__ w3,
        ushort* __restrict__ o0, ushort* __restrict__ o1,
        ushort* __restrict__ o2, ushort* __restrict__ o3) {
    const float* W; ushort* O;
    switch (blockIdx.z) {
        case 0:  W = w0; O = o0; break;
        case 1:  W = w1; O = o1; break;
        case 2:  W = w2; O = o2; break;
        default: W = w3; O = o3; break;
    }
    __shared__ ushort Ls[64][72];
    int t  = threadIdx.x;
    int n0 = blockIdx.x * 64;
    int k0 = blockIdx.y * 64;
#pragma unroll
    for (int i = 0; i < 4; ++i) {
        int kr = (t >> 4) + i * 16;
        float4 v = *(const float4*)(W + (size_t)(k0 + kr) * DM + n0 + (t & 15) * 4);
        Ls[(t & 15) * 4 + 0][kr] = f2bf(v.x);
        Ls[(t & 15) * 4 + 1][kr] = f2bf(v.y);
        Ls[(t & 15) * 4 + 2][kr] = f2bf(v.z);
        Ls[(t & 15) * 4 + 3][kr] = f2bf(v.w);
    }
    __syncthreads();
#pragma unroll
    for (int i = 0; i < 4; ++i) {
        int nl = (t >> 4) + i * 16;
        int k4 = (t & 15) * 4;
        ushort4 u;
        u.x = Ls[nl][k4 + 0]; u.y = Ls[nl][k4 + 1];
        u.z = Ls[nl][k4 + 2]; u.w = Ls[nl][k4 + 3];
        *(ushort4*)(O + (size_t)(n0 + nl) * DM + k0 + k4) = u;
    }
}

// ---------------------------------------------------------------------------
// Kernel 4: bf16-MFMA GEMM, C = A @ Wt^T + bias.
// MODE 0: fp32 [m][n]   (final output)
// MODE 1: bf16 [m][n]   (q, k)
// MODE 2: bf16 [n-global -> vbT row][m] (v, pre-transposed for attn PV)
// All epilogues bounce C through LDS for coalesced 16B global stores.
// ---------------------------------------------------------------------------
template <int MODE>
__global__ __launch_bounds__(256) void gemm_mfma(
        const ushort* __restrict__ A, const ushort* __restrict__ Bt,
        const float* __restrict__ bias, void* __restrict__ Cout) {
    __shared__ ushort As[64 * 64];
    __shared__ ushort Bs[64 * 64];
    constexpr int CF_N = (MODE == 0) ? 64 * 68 : 1;
    constexpr int CS_N = (MODE != 0) ? 64 * 72 : 1;
    __shared__ float  Cf[CF_N];
    __shared__ ushort Cs[CS_N];

    int t  = threadIdx.x;
    int w  = t >> 6;            // wave 0..3
    int ln = t & 63;
    int wr = w >> 1, wc = w & 1;
    int n0 = blockIdx.x * 64;
    int m0 = blockIdx.y * 64;

    f32x4 acc[2][2];
#pragma unroll
    for (int i = 0; i < 2; ++i)
#pragma unroll
        for (int j = 0; j < 2; ++j) acc[i][j] = (f32x4)0.0f;

    int row16 = ln & 15, kg = ln >> 4;

    for (int kb = 0; kb < DM; kb += 64) {
#pragma unroll
        for (int issue = 0; issue < 2; ++issue) {
            int chunk = issue * 256 + w * 64 + ln;      // 0..511 16B chunks
            int r = chunk >> 3, s = chunk & 7;
            int gcol = kb + ((s ^ (r & 7)) * 8);        // pre-swizzled source
            const ushort* ga = A  + (size_t)(m0 + r) * DM + gcol;
            const ushort* gb = Bt + (size_t)(n0 + r) * DM + gcol;
            __builtin_amdgcn_global_load_lds((const void*)ga,
                (void*)(As + (issue * 256 + w * 64) * 8), 16, 0, 0);
            __builtin_amdgcn_global_load_lds((const void*)gb,
                (void*)(Bs + (issue * 256 + w * 64) * 8), 16, 0, 0);
        }
        __syncthreads();
#pragma unroll
        for (int kk = 0; kk < 2; ++kk) {
            int swz = (kk * 32 + kg * 8) ^ ((row16 & 7) << 3);  // ushort idx in row
            bf16x8 af[2], bfr[2];
#pragma unroll
            for (int f = 0; f < 2; ++f) {
                int arow = 32 * wr + f * 16 + row16;
                af[f]  = *(const bf16x8*)&As[arow * 64 + swz];
                int brow = 32 * wc + f * 16 + row16;
                bfr[f] = *(const bf16x8*)&Bs[brow * 64 + swz];
            }
#pragma unroll
            for (int fr = 0; fr < 2; ++fr)
#pragma unroll
                for (int fc = 0; fc < 2; ++fc)
                    acc[fr][fc] = __builtin_amdgcn_mfma_f32_16x16x32_bf16(
                        af[fr], bfr[fc], acc[fr][fc], 0, 0, 0);
        }
        __syncthreads();
    }

    // epilogue: C/D layout col=lane&15 (n), row=(lane>>4)*4+reg (m)
    int col = ln & 15, rbase = (ln >> 4) * 4;
    if constexpr (MODE == 0) {
        float* C = (float*)Cout;
#pragma unroll
        for (int fc = 0; fc < 2; ++fc) {
            float bv = bias[n0 + 32 * wc + fc * 16 + col];
#pragma unroll
            for (int fr = 0; fr < 2; ++fr)
#pragma unroll
                for (int reg = 0; reg < 4; ++reg)
                    Cf[(32 * wr + 16 * fr + rbase + reg) * 68 + 32 * wc + 16 * fc + col]
                        = acc[fr][fc][reg] + bv;
        }
        __syncthreads();
#pragma unroll
        for (int i = 0; i < 4; ++i) {
            int c = i * 256 + t;
            int row = c >> 4, s = c & 15;
            *(float4*)&C[(size_t)(m0 + row) * DM + n0 + s * 4] = *(float4*)&Cf[row * 68 + s * 4];
        }
    } else if constexpr (MODE == 1) {
        ushort* C = (ushort*)Cout;
#pragma unroll
        for (int fc = 0; fc < 2; ++fc) {
            float bv = bias[n0 + 32 * wc + fc * 16 + col];
#pragma unroll
            for (int fr = 0; fr < 2; ++fr)
#pragma unroll
                for (int reg = 0; reg < 4; ++reg)
                    Cs[(32 * wr + 16 * fr + rbase + reg) * 72 + 32 * wc + 16 * fc + col]
                        = f2bf(acc[fr][fc][reg] + bv);
        }
        __syncthreads();
#pragma unroll
        for (int i = 0; i < 2; ++i) {
            int c = i * 256 + t;
            int row = c >> 3, s = c & 7;
            *(bf16x8*)&C[(size_t)(m0 + row) * DM + n0 + s * 8] = *(const bf16x8*)&Cs[row * 72 + s * 8];
        }
    } else {
        ushort* C = (ushort*)Cout;   // vbT base: rows (b*8+h)*64+d, cols tok
#pragma unroll
        for (int fc = 0; fc < 2; ++fc) {
            float bv = bias[n0 + 32 * wc + fc * 16 + col];
#pragma unroll
            for (int fr = 0; fr < 2; ++fr) {
                ushort4 u;
                u.x = f2bf(acc[fr][fc][0] + bv);
                u.y = f2bf(acc[fr][fc][1] + bv);
                u.z = f2bf(acc[fr][fc][2] + bv);
                u.w = f2bf(acc[fr][fc][3] + bv);
                *(ushort4*)&Cs[(32 * wc + 16 * fc + col) * 72 + 32 * wr + 16 * fr + rbase] = u;
            }
        }
        __syncthreads();
#pragma unroll
        for (int i = 0; i < 2; ++i) {
            int c = i * 256 + t;
            int row = c >> 3, s = c & 7;   // row = n-local (d), content along m (tok)
            *(bf16x8*)&C[((size_t)((m0 >> 10) * DM + n0 + row)) * T_SEQ + (m0 & 1023) + s * 8]
                = *(const bf16x8*)&Cs[row * 72 + s * 8];
        }
    }
}

// ---------------------------------------------------------------------------
// Kernel 5: MFMA flash attention, swapped-operand S^T = mfma(K, Q).
// Block = (q-tile 64, head, batch), 4 waves; wave owns 16 q-rows.
// Lane layout: q = lane&15 (one q-row per lane), softmax lane-local + 2 shfl.
// K, Vt staged via global_load_lds + XOR swizzle, double-buffered.
// P bounced through per-wave LDS (stride 72) to reach the B-frag layout.
// ---------------------------------------------------------------------------
__global__ __launch_bounds__(256) void attn_mfma(
        const ushort* __restrict__ qb, const ushort* __restrict__ kb,
        const ushort* __restrict__ vt, const ushort* __restrict__ bins,
        const float* __restrict__ rpe, ushort* __restrict__ outb) {
    __shared__ ushort Ks[2][64 * 64];
    __shared__ ushort Vs[2][64 * 64];
    __shared__ ushort Ps[4][16 * 72];
    __shared__ float tbl[64];

    const int t  = threadIdx.x;
    const int w  = t >> 6, ln = t & 63;
    const int g  = ln >> 4, cq = ln & 15;
    const int qt = blockIdx.x, h = blockIdx.y, b = blockIdx.z;
    const int q0 = qt * 64;

    if (t < 64) tbl[t] = rpe[t * NH + h];

    // Q B-frags (lane: q-row = cq, d = g*8 + j + kc*32) — loaded once
    bf16x8 qf[2];
    {
        const ushort* qrow = qb + ((size_t)(b * T_SEQ + q0 + w * 16 + cq)) * DM + h * DH + g * 8;
        qf[0] = *(const bf16x8*)(qrow);
        qf[1] = *(const bf16x8*)(qrow + 32);
    }

    f32x4 oacc[4];
#pragma unroll
    for (int mb = 0; mb < 4; ++mb) oacc[mb] = (f32x4)0.0f;
    float m_run = -3.0e38f, l_run = 0.0f;

    const ushort* brow0 = bins + ((size_t)(b * T_SEQ + q0 + w * 16 + cq)) * T_SEQ;

    auto stage = [&](int buf, int kt2) {
        int k0 = kt2 * 64;
#pragma unroll
        for (int i = 0; i < 2; ++i) {
            int c = i * 256 + t;
            int r = c >> 3, s = c & 7;
            int cc = (s ^ (r & 7)) * 8;                 // pre-swizzled source col
            const ushort* gk = kb + ((size_t)(b * T_SEQ + k0 + r)) * DM + h * DH + cc;
            const ushort* gv = vt + ((size_t)((b * NH + h) * DH + r)) * T_SEQ + k0 + cc;
            __builtin_amdgcn_global_load_lds((const void*)gk,
                (void*)&Ks[buf][(i * 256 + w * 64) * 8], 16, 0, 0);
            __builtin_amdgcn_global_load_lds((const void*)gv,
                (void*)&Vs[buf][(i * 256 + w * 64) * 8], 16, 0, 0);
        }
    };

    stage(0, 0);
    __syncthreads();   // compiler drains vmcnt before s_barrier -> tile 0 ready

    for (int kt = 0; kt < 16; ++kt) {
        int cur = kt & 1;
        if (kt < 15) stage(cur ^ 1, kt + 1);   // async prefetch into alt buffer
        const ushort* K = Ks[cur];
        const ushort* V = Vs[cur];

        // S^T[kv][q] = K·Q^T : acc over kc, 4 kv-blocks
        f32x4 sacc[4];
#pragma unroll
        for (int kvb = 0; kvb < 4; ++kvb) sacc[kvb] = (f32x4)0.0f;
#pragma unroll
        for (int kc = 0; kc < 2; ++kc)
#pragma unroll
            for (int kvb = 0; kvb < 4; ++kvb) {
                bf16x8 kf = *(const bf16x8*)
                    &K[(kvb * 16 + cq) * 64 + (((g + 4 * kc) ^ (cq & 7)) * 8)];
                sacc[kvb] = __builtin_amdgcn_mfma_f32_16x16x32_bf16(
                    kf, qf[kc], sacc[kvb], 0, 0, 0);
            }

        // bias + online softmax; lane's q = cq, kv = kvb*16 + g*4 + reg
        const ushort* brow = brow0 + kt * 64;
        float sv[16];
        float pm = -3.0e38f;
#pragma unroll
        for (int kvb = 0; kvb < 4; ++kvb) {
            ushort4 bi = *(const ushort4*)&brow[kvb * 16 + g * 4];
            ushort bb[4] = {bi.x, bi.y, bi.z, bi.w};
#pragma unroll
            for (int r = 0; r < 4; ++r) {
                float s = sacc[kvb][r] * 0.125f + tbl[bb[r] & 63] + tbl[bb[r] >> 8];
                sv[kvb * 4 + r] = s;
                pm = fmaxf(pm, s);
            }
        }
        pm = fmaxf(pm, __shfl_xor(pm, 16));
        pm = fmaxf(pm, __shfl_xor(pm, 32));
        float mnew  = fmaxf(m_run, pm);
        float alpha = __expf(m_run - mnew);
        float psum  = 0.0f;
        ushort pk[16];
#pragma unroll
        for (int i = 0; i < 16; ++i) {
            float p = __expf(sv[i] - mnew);
            psum += p;
            pk[i] = f2bf(p);
        }
        psum += __shfl_xor(psum, 16);
        psum += __shfl_xor(psum, 32);
        l_run = l_run * alpha + psum;
        m_run = mnew;
#pragma unroll
        for (int mb = 0; mb < 4; ++mb) oacc[mb] *= alpha;

        // P[q][kv] bf16 -> per-wave LDS (stride 72: 2-way-free writes)
        ushort* Pw = &Ps[w][0];
#pragma unroll
        for (int kvb = 0; kvb < 4; ++kvb) {
            ushort4 u;
            u.x = pk[kvb * 4 + 0]; u.y = pk[kvb * 4 + 1];
            u.z = pk[kvb * 4 + 2]; u.w = pk[kvb * 4 + 3];
            *(ushort4*)&Pw[cq * 72 + kvb * 16 + g * 4] = u;
        }
        asm volatile("s_waitcnt lgkmcnt(0)" ::: "memory");
        __builtin_amdgcn_sched_barrier(0);

        // O^T[d][q] += Vt·P^T : A-frag = Vt (m=d), B-frag = P (n=q)
#pragma unroll
        for (int kc = 0; kc < 2; ++kc) {
            bf16x8 pf = *(const bf16x8*)&Pw[cq * 72 + kc * 32 + g * 8];
#pragma unroll
            for (int mb = 0; mb < 4; ++mb) {
                bf16x8 vf = *(const bf16x8*)
                    &V[(mb * 16 + cq) * 64 + (((g + 4 * kc) ^ (cq & 7)) * 8)];
                oacc[mb] = __builtin_amdgcn_mfma_f32_16x16x32_bf16(
                    vf, pf, oacc[mb], 0, 0, 0);
            }
        }
        __syncthreads();   // drains prefetch vmcnt + joins waves before buffer reuse
    }

    // epilogue: lane holds O^T at (q=cq, d=mb*16+4g+reg); bounce via LDS
    float inv = 1.0f / l_run;
    ushort* Ow = &Ps[w][0];
#pragma unroll
    for (int mb = 0; mb < 4; ++mb) {
        ushort4 u;
        u.x = f2bf(oacc[mb][0] * inv);
        u.y = f2bf(oacc[mb][1] * inv);
        u.z = f2bf(oacc[mb][2] * inv);
        u.w = f2bf(oacc[mb][3] * inv);
        *(ushort4*)&Ow[cq * 72 + mb * 16 + g * 4] = u;
    }
    asm volatile("s_waitcnt lgkmcnt(0)" ::: "memory");
    __builtin_amdgcn_sched_barrier(0);
#pragma unroll
    for (int i = 0; i < 2; ++i) {
        int c = i * 64 + ln;
        int row = c >> 3, s = c & 7;
        bf16x8 val = *(const bf16x8*)&Ow[row * 72 + s * 8];
        *(bf16x8*)&outb[((size_t)(b * T_SEQ + q0 + w * 16 + row)) * DM + h * DH + s * 8] = val;
    }
}

// ---------------------------------------------------------------------------
extern "C" void kernel_launch(void* const* d_in, const int* in_sizes, int n_in,
                              void* d_out, int out_size, void* d_ws, size_t ws_size,
                              hipStream_t stream) {
    const float* p       = (const float*)d_in[0];
    const float* pcoords = (const float*)d_in[1];
    const float* rpe     = (const float*)d_in[2];
    const float* wq_w    = (const float*)d_in[3];
    const float* wq_b    = (const float*)d_in[4];
    const float* wk_w    = (const float*)d_in[5];
    const float* wk_b    = (const float*)d_in[6];
    const float* wv_w    = (const float*)d_in[7];
    const float* wv_b    = (const float*)d_in[8];
    const float* wo_w    = (const float*)d_in[9];
    const float* wo_b    = (const float*)d_in[10];
    float* out = (float*)d_out;

    const size_t NE = (size_t)NTOK * DM;      // 2M elems
    ushort* pb   = (ushort*)d_ws;             // bf16 p            [4096][512]
    ushort* qb16 = pb + NE;                   // bf16 q            [4096][512]
    ushort* kb16 = qb16 + NE;                 // bf16 k            [4096][512]
    ushort* vbT  = kb16 + NE;                 // bf16 v^T          [(b*8+h)*64+d][1024]
    ushort* ab   = vbT + NE;                  // bf16 attn out     [4096][512]
    ushort* wt0  = ab + NE;                   // bf16 W^T          [512][512] x4
    ushort* wt1  = wt0 + (size_t)DM * DM;
    ushort* wt2  = wt1 + (size_t)DM * DM;
    ushort* wt3  = wt2 + (size_t)DM * DM;
    ushort* bins = wt3 + (size_t)DM * DM;     // u16 packed bins   [4][1024][1024]
    float*  er   = (float*)(bins + (size_t)BATCH * T_SEQ * T_SEQ);

    eta_range_kernel<<<1, 256, 0, stream>>>(pcoords, er);
    cvt_bf16<<<NE / 1024, 256, 0, stream>>>(p, pb);
    cvtT_bf16<<<dim3(8, 8, 4), 256, 0, stream>>>(
        wq_w, wk_w, wv_w, wo_w, wt0, wt1, wt2, wt3);
    bins_kernel<<<dim3(64, BATCH), 256, 0, stream>>>(pcoords, er, bins);

    dim3 gg(DM / 64, NTOK / 64);
    gemm_mfma<1><<<gg, 256, 0, stream>>>(pb, wt0, wq_b, qb16);
    gemm_mfma<1><<<gg, 256, 0, stream>>>(pb, wt1, wk_b, kb16);
    gemm_mfma<2><<<gg, 256, 0, stream>>>(pb, wt2, wv_b, vbT);

    attn_mfma<<<dim3(16, NH, BATCH), 256, 0, stream>>>(
        qb16, kb16, vbT, bins, rpe, ab);

    gemm_mfma<0><<<gg, 256, 0, stream>>>(ab, wt3, wo_b, out);
}